// Round 14
// baseline (77.922 us; speedup 1.0000x reference)
//
#include <hip/hip_runtime.h>
#include <hip/hip_bf16.h>
#include <math.h>

#define B 16
#define V 100000
#define S 4096
#define BS (B * S)      // 65536
#define NT 256          // mfma block threads (4 waves)
#define ROUNDS 4        // R14 ONLY: x4 in-kernel replay to force counter visibility
#define ONE_BF 0x3F80u  // 1.0 in bf16

typedef __attribute__((ext_vector_type(8))) short bf16x8;
typedef __attribute__((ext_vector_type(16))) float f32x16;

static __device__ __forceinline__ unsigned bft(float x) {
  return __float_as_uint(x) >> 16;  // truncating f32 -> bf16 bits
}
static __device__ __forceinline__ float bff(unsigned hbits) {
  return __uint_as_float(hbits << 16);
}
static __device__ __forceinline__ unsigned pk(unsigned lo, unsigned hi) {
  return (lo & 0xFFFFu) | (hi << 16);
}

// ws layout (floats):
//   part_src[16][BS] @ 0       (4 MB)
//   part_dst[4][BS]  @ 16*BS   (1 MB)
//   srcfrag          @ 21*BS   (2 MB)  B-frags, [tile][lane] uint4
//   dstfrag          @ 29*BS   (2 MB)  A-frags, [point][h] uint4

// ---------------------------------------------------------------------------
// Prep: 2 points per thread (6 outstanding vertex loads -> 2x MLP for the
// latency-bound random gather). Grid 256 x 256thr covers 2*BS points.
// ---------------------------------------------------------------------------
__global__ __launch_bounds__(256) void chamfer_prep_kernel(
    const float* __restrict__ src_verts, const float* __restrict__ dst_verts,
    const int* __restrict__ src_idx, const int* __restrict__ dst_idx,
    uint4* __restrict__ srcfrag, uint4* __restrict__ dstfrag,
    float* __restrict__ out) {
  int t = blockIdx.x * 256 + threadIdx.x;  // 0..65535
  if (t == 0) *out = 0.f;
  int set = t >> 15;            // 32768 pair-threads per set
  int i0 = (t & 32767) * 2;     // points i0, i0+1 (same b: S even)
  int b = i0 >> 12;

  const int* idx = set ? dst_idx : src_idx;
  const float* verts = set ? dst_verts : src_verts;
  int v0 = idx[i0], v1 = idx[i0 + 1];
  v0 = v0 < 0 ? 0 : (v0 >= V ? V - 1 : v0);
  v1 = v1 < 0 ? 0 : (v1 >= V ? V - 1 : v1);
  const float* p0 = verts + ((size_t)b * V + v0) * 3;
  const float* p1 = verts + ((size_t)b * V + v1) * 3;
  float x0 = p0[0], y0 = p0[1], z0 = p0[2];
  float x1 = p1[0], y1 = p1[1], z1 = p1[2];

  #pragma unroll
  for (int k = 0; k < 2; ++k) {
    float x = k ? x1 : x0, y = k ? y1 : y0, z = k ? z1 : z0;
    int i = i0 + k;
    unsigned hx = bft(x), hy = bft(y), hz = bft(z);
    float n2 = x * x + y * y + z * z;
    unsigned n2h = bft(n2);
    unsigned n2l = bft(n2 - bff(n2h));
    if (set == 0) {
      unsigned lx = bft(x - bff(hx)), ly = bft(y - bff(hy)), lz = bft(z - bff(hz));
      int tile = i >> 5, c = i & 31;
      uint4* base = srcfrag + (size_t)tile * 64;
      base[c]      = make_uint4(pk(hx, hy), pk(hz, lx), pk(ly, lz), pk(hx, hy));
      base[32 + c] = make_uint4(pk(hz, n2h), pk(n2l, ONE_BF), pk(ONE_BF, 0u), 0u);
    } else {
      unsigned mx = bft(-2.f * bff(hx)), my = bft(-2.f * bff(hy)), mz = bft(-2.f * bff(hz));
      unsigned nx = bft(-2.f * (x - bff(hx)));
      unsigned ny = bft(-2.f * (y - bff(hy)));
      unsigned nz = bft(-2.f * (z - bff(hz)));
      dstfrag[(size_t)i * 2]     = make_uint4(pk(mx, my), pk(mz, mx), pk(my, mz), pk(nx, ny));
      dstfrag[(size_t)i * 2 + 1] = make_uint4(pk(nz, ONE_BF), pk(ONE_BF, n2h), pk(n2l, 0u), 0u);
    }
  }
}

// ---------------------------------------------------------------------------
// Fused kernel: R13 body, replayed ROUNDS times inside one dispatch so the
// dispatch (~4x17.7us) outranks the ~40us harness fills in the counter
// profile. Idempotent: every round recomputes identical plane values.
// ---------------------------------------------------------------------------
__global__ __launch_bounds__(NT, 4) void chamfer_mfma_kernel(
    const uint4* __restrict__ srcfrag, const uint4* __restrict__ dstfrag,
    float* __restrict__ part_src, float* __restrict__ part_dst) {
  __shared__ struct {
    uint4 sfrag[2048];   // 32 KB
    unsigned smin[1024]; // 4 KB
  } sh;
  float* red = (float*)sh.sfrag;  // epilogue overlay (corrupts sfrag -> restage)

  int bid = blockIdx.x;
  int b = bid >> 6;
  int jp = (bid >> 2) & 15;
  int iq = bid & 3;
  int tid = threadIdx.x;

  int w = tid >> 6;
  int lane = tid & 63;
  int c = lane & 31, h = lane >> 5;
  int gj = b * S + jp * 256 + w * 64 + c;
  bf16x8 A0 = __builtin_bit_cast(bf16x8, dstfrag[(size_t)gj * 2 + h]);
  bf16x8 A1 = __builtin_bit_cast(bf16x8, dstfrag[(size_t)(gj + 32) * 2 + h]);

  const uint4* chunk = srcfrag + (size_t)(b * 128 + iq * 32) * 64;

  #pragma unroll 1
  for (int round = 0; round < ROUNDS; ++round) {
    // ---- stage
    #pragma unroll
    for (int k = 0; k < 8; ++k) {
      sh.sfrag[tid + k * NT] = chunk[tid + k * NT];
    }
    #pragma unroll
    for (int k = 0; k < 4; ++k) sh.smin[tid + k * NT] = 0x7F800000u;
    __syncthreads();

    f32x16 zero = {};
    f32x16 mn0, mn1;
    #pragma unroll
    for (int r = 0; r < 16; ++r) { mn0[r] = INFINITY; mn1[r] = INFINITY; }

    int t0r = 8 * w;
    #pragma unroll 4
    for (int it = 0; it < 32; ++it) {
      int t = (it + t0r) & 31;
      bf16x8 Bf = __builtin_bit_cast(bf16x8, sh.sfrag[t * 64 + lane]);
      f32x16 d0 = __builtin_amdgcn_mfma_f32_32x32x16_bf16(A0, Bf, zero, 0, 0, 0);
      f32x16 d1 = __builtin_amdgcn_mfma_f32_32x32x16_bf16(A1, Bf, zero, 0, 0, 0);
      #pragma unroll
      for (int r = 0; r < 16; ++r) mn0[r] = fminf(mn0[r], d0[r]);
      #pragma unroll
      for (int r = 0; r < 16; ++r) mn1[r] = fminf(mn1[r], d1[r]);
      float t0 = fminf(fminf(d0[0], d0[1]), d0[2]);
      float t1 = fminf(fminf(d0[3], d0[4]), d0[5]);
      float t2 = fminf(fminf(d0[6], d0[7]), d0[8]);
      float t3 = fminf(fminf(d0[9], d0[10]), d0[11]);
      float t4 = fminf(fminf(d0[12], d0[13]), d0[14]);
      float s0 = fminf(fminf(d1[0], d1[1]), d1[2]);
      float s1 = fminf(fminf(d1[3], d1[4]), d1[5]);
      float s2 = fminf(fminf(d1[6], d1[7]), d1[8]);
      float s3 = fminf(fminf(d1[9], d1[10]), d1[11]);
      float s4 = fminf(fminf(d1[12], d1[13]), d1[14]);
      float m0 = fminf(fminf(fminf(t0, t1), fminf(t2, t3)), fminf(t4, d0[15]));
      float m1 = fminf(fminf(fminf(s0, s1), fminf(s2, s3)), fminf(s4, d1[15]));
      float m = fminf(m0, m1);
      atomicMin(&sh.smin[t * 32 + c], __float_as_uint(fmaxf(m, 0.f)));
    }

    // ---- src-direction flush
    __syncthreads();
    #pragma unroll
    for (int k = 0; k < 4; ++k) {
      int p = tid + k * NT;
      part_src[jp * BS + b * S + iq * 1024 + p] = __uint_as_float(sh.smin[p]);
    }
    __syncthreads();

    // ---- dst-direction: LDS transpose (stride 33) + fold + store
    #pragma unroll
    for (int r = 0; r < 16; ++r) {
      int row = w * 64 + (r & 3) + 8 * (r >> 2) + 4 * h;
      red[row * 33 + c] = mn0[r];
      red[(row + 32) * 33 + c] = mn1[r];
    }
    __syncthreads();
    {
      int row = tid;
      const float* rp = red + row * 33;
      float a0 = fminf(fminf(rp[0], rp[1]), rp[2]);
      float a1 = fminf(fminf(rp[3], rp[4]), rp[5]);
      float a2 = fminf(fminf(rp[6], rp[7]), rp[8]);
      float a3 = fminf(fminf(rp[9], rp[10]), rp[11]);
      float a4 = fminf(fminf(rp[12], rp[13]), rp[14]);
      float a5 = fminf(fminf(rp[15], rp[16]), rp[17]);
      float a6 = fminf(fminf(rp[18], rp[19]), rp[20]);
      float a7 = fminf(fminf(rp[21], rp[22]), rp[23]);
      float a8 = fminf(fminf(rp[24], rp[25]), rp[26]);
      float a9 = fminf(fminf(rp[27], rp[28]), rp[29]);
      float aa = fminf(rp[30], rp[31]);
      float m = fminf(fminf(fminf(fminf(a0, a1), fminf(a2, a3)),
                            fminf(fminf(a4, a5), fminf(a6, a7))),
                      fminf(fminf(a8, a9), aa));
      part_dst[iq * BS + b * S + jp * 256 + row] = fmaxf(m, 0.f);
    }
    __syncthreads();  // protect next round's restage vs red readers
  }
}

// ---------------------------------------------------------------------------
// Reduce: 128 blocks x 128 thr (2x BW vs 64 blocks), fold 16 src + 4 dst
// planes, one atomicAdd per block (128 total).
// ---------------------------------------------------------------------------
__global__ __launch_bounds__(128) void chamfer_reduce_kernel(
    const float* __restrict__ parts, float* __restrict__ out) {
  __shared__ float red[2];
  int tid = threadIdx.x;
  int i4 = blockIdx.x * 128 + tid;  // 16384 float4 slots = BS floats

  const float4* ps = (const float4*)parts;             // 16 src planes
  const float4* pd = (const float4*)(parts + 16 * BS); // 4 dst planes

  float4 ms = ps[i4];
  #pragma unroll
  for (int j = 1; j < 16; ++j) {
    float4 t = ps[j * (BS / 4) + i4];
    ms.x = fminf(ms.x, t.x); ms.y = fminf(ms.y, t.y);
    ms.z = fminf(ms.z, t.z); ms.w = fminf(ms.w, t.w);
  }
  float4 md = pd[i4];
  #pragma unroll
  for (int j = 1; j < 4; ++j) {
    float4 t = pd[j * (BS / 4) + i4];
    md.x = fminf(md.x, t.x); md.y = fminf(md.y, t.y);
    md.z = fminf(md.z, t.z); md.w = fminf(md.w, t.w);
  }
  float v = (ms.x + ms.y + ms.z + ms.w) + (md.x + md.y + md.z + md.w);
  v *= (1.0f / (float)BS);

  #pragma unroll
  for (int off = 32; off > 0; off >>= 1) v += __shfl_down(v, off, 64);
  if ((tid & 63) == 0) red[tid >> 6] = v;
  __syncthreads();
  if (tid == 0) atomicAdd(out, red[0] + red[1]);
}

extern "C" void kernel_launch(void* const* d_in, const int* in_sizes, int n_in,
                              void* d_out, int out_size, void* d_ws, size_t ws_size,
                              hipStream_t stream) {
  const float* src_verts = (const float*)d_in[0];
  const float* dst_verts = (const float*)d_in[1];
  const int* src_idx = (const int*)d_in[2];
  const int* dst_idx = (const int*)d_in[3];
  float* out = (float*)d_out;

  float* parts = (float*)d_ws;
  float* part_src = parts;                        // [16][BS]
  float* part_dst = parts + 16 * BS;              // [4][BS]
  uint4* srcfrag = (uint4*)(parts + 21 * BS);     // 2 MB
  uint4* dstfrag = (uint4*)(parts + 29 * BS);     // 2 MB

  chamfer_prep_kernel<<<256, 256, 0, stream>>>(
      src_verts, dst_verts, src_idx, dst_idx, srcfrag, dstfrag, out);

  chamfer_mfma_kernel<<<B * 16 * 4, NT, 0, stream>>>(
      srcfrag, dstfrag, part_src, part_dst);

  chamfer_reduce_kernel<<<128, 128, 0, stream>>>(parts, out);
}

// Round 16
// 30.750 us; speedup vs baseline: 2.5341x; 2.5341x over previous
//
#include <hip/hip_runtime.h>
#include <hip/hip_bf16.h>
#include <math.h>

#define B 16
#define V 100000
#define S 4096
#define BS (B * S)      // 65536
#define NT 256          // mfma block threads (4 waves)
#define ONE_BF 0x3F80u  // 1.0 in bf16

typedef __attribute__((ext_vector_type(8))) short bf16x8;
typedef __attribute__((ext_vector_type(16))) float f32x16;

static __device__ __forceinline__ unsigned bft(float x) {
  return __float_as_uint(x) >> 16;  // truncating f32 -> bf16 bits
}
static __device__ __forceinline__ float bff(unsigned hbits) {
  return __uint_as_float(hbits << 16);
}
static __device__ __forceinline__ unsigned pk(unsigned lo, unsigned hi) {
  return (lo & 0xFFFFu) | (hi << 16);
}
// min3 via fminf nest: clang fuses to v_min3_f32 WITH correct MFMA hazard
// handling. (R15's inline-asm version produced stale reads -> absmax 1.8e-2.)
static __device__ __forceinline__ float min3(float a, float b, float c) {
  return fminf(fminf(a, b), c);
}

// ws layout (floats):
//   part_src[16][BS] @ 0       (4 MB)
//   part_dst[4][BS]  @ 16*BS   (1 MB)
//   srcfrag          @ 21*BS   (2 MB)  B-frags, [tile][lane] uint4
//   dstfrag          @ 29*BS   (2 MB)  A-frags, [point][h] uint4

// ---------------------------------------------------------------------------
// Prep: 2 points per thread (6 outstanding vertex loads).
// ---------------------------------------------------------------------------
__global__ __launch_bounds__(256) void chamfer_prep_kernel(
    const float* __restrict__ src_verts, const float* __restrict__ dst_verts,
    const int* __restrict__ src_idx, const int* __restrict__ dst_idx,
    uint4* __restrict__ srcfrag, uint4* __restrict__ dstfrag,
    float* __restrict__ out) {
  int t = blockIdx.x * 256 + threadIdx.x;  // 0..65535
  if (t == 0) *out = 0.f;
  int set = t >> 15;            // 32768 pair-threads per set
  int i0 = (t & 32767) * 2;     // points i0, i0+1 (same b: S even)
  int b = i0 >> 12;

  const int* idx = set ? dst_idx : src_idx;
  const float* verts = set ? dst_verts : src_verts;
  int v0 = idx[i0], v1 = idx[i0 + 1];
  v0 = v0 < 0 ? 0 : (v0 >= V ? V - 1 : v0);
  v1 = v1 < 0 ? 0 : (v1 >= V ? V - 1 : v1);
  const float* p0 = verts + ((size_t)b * V + v0) * 3;
  const float* p1 = verts + ((size_t)b * V + v1) * 3;
  float x0 = p0[0], y0 = p0[1], z0 = p0[2];
  float x1 = p1[0], y1 = p1[1], z1 = p1[2];

  #pragma unroll
  for (int k = 0; k < 2; ++k) {
    float x = k ? x1 : x0, y = k ? y1 : y0, z = k ? z1 : z0;
    int i = i0 + k;
    unsigned hx = bft(x), hy = bft(y), hz = bft(z);
    float n2 = x * x + y * y + z * z;
    unsigned n2h = bft(n2);
    unsigned n2l = bft(n2 - bff(n2h));
    if (set == 0) {
      unsigned lx = bft(x - bff(hx)), ly = bft(y - bff(hy)), lz = bft(z - bff(hz));
      int tile = i >> 5, c = i & 31;
      uint4* base = srcfrag + (size_t)tile * 64;
      base[c]      = make_uint4(pk(hx, hy), pk(hz, lx), pk(ly, lz), pk(hx, hy));
      base[32 + c] = make_uint4(pk(hz, n2h), pk(n2l, ONE_BF), pk(ONE_BF, 0u), 0u);
    } else {
      unsigned mx = bft(-2.f * bff(hx)), my = bft(-2.f * bff(hy)), mz = bft(-2.f * bff(hz));
      unsigned nx = bft(-2.f * (x - bff(hx)));
      unsigned ny = bft(-2.f * (y - bff(hy)));
      unsigned nz = bft(-2.f * (z - bff(hz)));
      dstfrag[(size_t)i * 2]     = make_uint4(pk(mx, my), pk(mz, mx), pk(my, mz), pk(nx, ny));
      dstfrag[(size_t)i * 2 + 1] = make_uint4(pk(nz, ONE_BF), pk(ONE_BF, n2h), pk(n2l, 0u), 0u);
    }
  }
}

// ---------------------------------------------------------------------------
// Fused kernel. __launch_bounds__(256, 2): 256-reg budget so the live set
// (A 8 + mn 32 + d 32 + temps) stays all-VGPR — R14 counters (VGPR_Count=64)
// proved the 128-cap forced AGPR-form MFMA with v_accvgpr_read before every
// mn-fold (+32 VALU/iter). min3 = fminf nest (compiler-fused v_min3_f32).
// ---------------------------------------------------------------------------
__global__ __launch_bounds__(NT, 2) void chamfer_mfma_kernel(
    const uint4* __restrict__ srcfrag, const uint4* __restrict__ dstfrag,
    float* __restrict__ part_src, float* __restrict__ part_dst) {
  __shared__ struct {
    uint4 sfrag[2048];   // 32 KB
    unsigned smin[1024]; // 4 KB
  } sh;
  float* red = (float*)sh.sfrag;  // epilogue overlay

  int bid = blockIdx.x;
  int b = bid >> 6;
  int jp = (bid >> 2) & 15;
  int iq = bid & 3;
  int tid = threadIdx.x;

  // ---- stage: coalesced 32 KB copy
  const uint4* chunk = srcfrag + (size_t)(b * 128 + iq * 32) * 64;
  #pragma unroll
  for (int k = 0; k < 8; ++k) {
    sh.sfrag[tid + k * NT] = chunk[tid + k * NT];
  }
  #pragma unroll
  for (int k = 0; k < 4; ++k) sh.smin[tid + k * NT] = 0x7F800000u;  // +INF

  // ---- A-fragments: two dst tiles per wave, fixed all loop
  int w = tid >> 6;
  int lane = tid & 63;
  int c = lane & 31, h = lane >> 5;
  int gj = b * S + jp * 256 + w * 64 + c;
  bf16x8 A0 = __builtin_bit_cast(bf16x8, dstfrag[(size_t)gj * 2 + h]);
  bf16x8 A1 = __builtin_bit_cast(bf16x8, dstfrag[(size_t)(gj + 32) * 2 + h]);

  __syncthreads();

  f32x16 zero = {};
  f32x16 mn0, mn1;
  #pragma unroll
  for (int r = 0; r < 16; ++r) { mn0[r] = INFINITY; mn1[r] = INFINITY; }

  int t0r = 8 * w;  // per-wave rotation offset
  #pragma unroll 4
  for (int it = 0; it < 32; ++it) {
    int t = (it + t0r) & 31;
    bf16x8 Bf = __builtin_bit_cast(bf16x8, sh.sfrag[t * 64 + lane]);
    f32x16 d0 = __builtin_amdgcn_mfma_f32_32x32x16_bf16(A0, Bf, zero, 0, 0, 0);
    f32x16 d1 = __builtin_amdgcn_mfma_f32_32x32x16_bf16(A1, Bf, zero, 0, 0, 0);
    #pragma unroll
    for (int r = 0; r < 16; ++r) mn0[r] = fminf(mn0[r], d0[r]);
    #pragma unroll
    for (int r = 0; r < 16; ++r) mn1[r] = fminf(mn1[r], d1[r]);
    // src-direction: fold 64 rows for column (t, c) — min3 tree
    float t0 = min3(d0[0], d0[1], d0[2]);
    float t1 = min3(d0[3], d0[4], d0[5]);
    float t2 = min3(d0[6], d0[7], d0[8]);
    float t3 = min3(d0[9], d0[10], d0[11]);
    float t4 = min3(d0[12], d0[13], d0[14]);
    float u0 = min3(t0, t1, t2);
    float u1 = min3(t3, t4, d0[15]);
    float s0 = min3(d1[0], d1[1], d1[2]);
    float s1 = min3(d1[3], d1[4], d1[5]);
    float s2 = min3(d1[6], d1[7], d1[8]);
    float s3 = min3(d1[9], d1[10], d1[11]);
    float s4 = min3(d1[12], d1[13], d1[14]);
    float v0 = min3(s0, s1, s2);
    float v1 = min3(s3, s4, d1[15]);
    float m = fminf(min3(u0, u1, v0), v1);
    atomicMin(&sh.smin[t * 32 + c], __float_as_uint(fmaxf(m, 0.f)));
  }

  // ---- src-direction flush
  __syncthreads();
  #pragma unroll
  for (int k = 0; k < 4; ++k) {
    int p = tid + k * NT;
    part_src[jp * BS + b * S + iq * 1024 + p] = __uint_as_float(sh.smin[p]);
  }
  __syncthreads();

  // ---- dst-direction: LDS transpose (stride 33) + fold + store
  #pragma unroll
  for (int r = 0; r < 16; ++r) {
    int row = w * 64 + (r & 3) + 8 * (r >> 2) + 4 * h;  // 32x32 C/D layout
    red[row * 33 + c] = mn0[r];
    red[(row + 32) * 33 + c] = mn1[r];
  }
  __syncthreads();
  {
    int row = tid;
    const float* rp = red + row * 33;
    float a0 = min3(rp[0], rp[1], rp[2]);
    float a1 = min3(rp[3], rp[4], rp[5]);
    float a2 = min3(rp[6], rp[7], rp[8]);
    float a3 = min3(rp[9], rp[10], rp[11]);
    float a4 = min3(rp[12], rp[13], rp[14]);
    float a5 = min3(rp[15], rp[16], rp[17]);
    float a6 = min3(rp[18], rp[19], rp[20]);
    float a7 = min3(rp[21], rp[22], rp[23]);
    float a8 = min3(rp[24], rp[25], rp[26]);
    float a9 = min3(rp[27], rp[28], rp[29]);
    float aa = fminf(rp[30], rp[31]);
    float b0 = min3(a0, a1, a2);
    float b1 = min3(a3, a4, a5);
    float b2 = min3(a6, a7, a8);
    float b3 = min3(a9, aa, b0);
    float m = min3(b1, b2, b3);
    part_dst[iq * BS + b * S + jp * 256 + row] = fmaxf(m, 0.f);
  }
}

// ---------------------------------------------------------------------------
// Reduce: 128 blocks x 128 thr, fold 16 src + 4 dst planes, one atomicAdd
// per block (128 total — cheap per R7).
// ---------------------------------------------------------------------------
__global__ __launch_bounds__(128) void chamfer_reduce_kernel(
    const float* __restrict__ parts, float* __restrict__ out) {
  __shared__ float red[2];
  int tid = threadIdx.x;
  int i4 = blockIdx.x * 128 + tid;  // 16384 float4 slots = BS floats

  const float4* ps = (const float4*)parts;             // 16 src planes
  const float4* pd = (const float4*)(parts + 16 * BS); // 4 dst planes

  float4 ms = ps[i4];
  #pragma unroll
  for (int j = 1; j < 16; ++j) {
    float4 t = ps[j * (BS / 4) + i4];
    ms.x = fminf(ms.x, t.x); ms.y = fminf(ms.y, t.y);
    ms.z = fminf(ms.z, t.z); ms.w = fminf(ms.w, t.w);
  }
  float4 md = pd[i4];
  #pragma unroll
  for (int j = 1; j < 4; ++j) {
    float4 t = pd[j * (BS / 4) + i4];
    md.x = fminf(md.x, t.x); md.y = fminf(md.y, t.y);
    md.z = fminf(md.z, t.z); md.w = fminf(md.w, t.w);
  }
  float v = (ms.x + ms.y + ms.z + ms.w) + (md.x + md.y + md.z + md.w);
  v *= (1.0f / (float)BS);

  #pragma unroll
  for (int off = 32; off > 0; off >>= 1) v += __shfl_down(v, off, 64);
  if ((tid & 63) == 0) red[tid >> 6] = v;
  __syncthreads();
  if (tid == 0) atomicAdd(out, red[0] + red[1]);
}

extern "C" void kernel_launch(void* const* d_in, const int* in_sizes, int n_in,
                              void* d_out, int out_size, void* d_ws, size_t ws_size,
                              hipStream_t stream) {
  const float* src_verts = (const float*)d_in[0];
  const float* dst_verts = (const float*)d_in[1];
  const int* src_idx = (const int*)d_in[2];
  const int* dst_idx = (const int*)d_in[3];
  float* out = (float*)d_out;

  float* parts = (float*)d_ws;
  float* part_src = parts;                        // [16][BS]
  float* part_dst = parts + 16 * BS;              // [4][BS]
  uint4* srcfrag = (uint4*)(parts + 21 * BS);     // 2 MB
  uint4* dstfrag = (uint4*)(parts + 29 * BS);     // 2 MB

  chamfer_prep_kernel<<<256, 256, 0, stream>>>(
      src_verts, dst_verts, src_idx, dst_idx, srcfrag, dstfrag, out);

  chamfer_mfma_kernel<<<B * 16 * 4, NT, 0, stream>>>(
      srcfrag, dstfrag, part_src, part_dst);

  chamfer_reduce_kernel<<<128, 128, 0, stream>>>(parts, out);
}

// Round 17
// 30.663 us; speedup vs baseline: 2.5412x; 1.0028x over previous
//
#include <hip/hip_runtime.h>
#include <hip/hip_bf16.h>
#include <math.h>

#define B 16
#define V 100000
#define S 4096
#define BS (B * S)      // 65536
#define NT 256          // mfma block threads (4 waves)
#define ONE_BF 0x3F80u  // 1.0 in bf16

typedef __attribute__((ext_vector_type(8))) short bf16x8;
typedef __attribute__((ext_vector_type(16))) float f32x16;

static __device__ __forceinline__ unsigned bft(float x) {
  return __float_as_uint(x) >> 16;  // truncating f32 -> bf16 bits
}
static __device__ __forceinline__ float bff(unsigned hbits) {
  return __uint_as_float(hbits << 16);
}
static __device__ __forceinline__ unsigned pk(unsigned lo, unsigned hi) {
  return (lo & 0xFFFFu) | (hi << 16);
}
// fminf nests fuse to v_min3_f32 with correct MFMA hazards (R15 lesson:
// never inline-asm this).
static __device__ __forceinline__ float min3(float a, float b, float c) {
  return fminf(fminf(a, b), c);
}

// ws layout (floats):
//   part_src[16][BS] @ 0       (4 MB)
//   part_dst[4][BS]  @ 16*BS   (1 MB)
//   srcfrag          @ 21*BS   (2 MB)  B-frags, [tile][lane] uint4
//   dstfrag          @ 29*BS   (2 MB)  A-frags, [point][h] uint4

// ---------------------------------------------------------------------------
// Prep: 2 points per thread (6 outstanding vertex loads).
// ---------------------------------------------------------------------------
__global__ __launch_bounds__(256) void chamfer_prep_kernel(
    const float* __restrict__ src_verts, const float* __restrict__ dst_verts,
    const int* __restrict__ src_idx, const int* __restrict__ dst_idx,
    uint4* __restrict__ srcfrag, uint4* __restrict__ dstfrag,
    float* __restrict__ out) {
  int t = blockIdx.x * 256 + threadIdx.x;  // 0..65535
  if (t == 0) *out = 0.f;
  int set = t >> 15;            // 32768 pair-threads per set
  int i0 = (t & 32767) * 2;     // points i0, i0+1 (same b: S even)
  int b = i0 >> 12;

  const int* idx = set ? dst_idx : src_idx;
  const float* verts = set ? dst_verts : src_verts;
  int v0 = idx[i0], v1 = idx[i0 + 1];
  v0 = v0 < 0 ? 0 : (v0 >= V ? V - 1 : v0);
  v1 = v1 < 0 ? 0 : (v1 >= V ? V - 1 : v1);
  const float* p0 = verts + ((size_t)b * V + v0) * 3;
  const float* p1 = verts + ((size_t)b * V + v1) * 3;
  float x0 = p0[0], y0 = p0[1], z0 = p0[2];
  float x1 = p1[0], y1 = p1[1], z1 = p1[2];

  #pragma unroll
  for (int k = 0; k < 2; ++k) {
    float x = k ? x1 : x0, y = k ? y1 : y0, z = k ? z1 : z0;
    int i = i0 + k;
    unsigned hx = bft(x), hy = bft(y), hz = bft(z);
    float n2 = x * x + y * y + z * z;
    unsigned n2h = bft(n2);
    unsigned n2l = bft(n2 - bff(n2h));
    if (set == 0) {
      unsigned lx = bft(x - bff(hx)), ly = bft(y - bff(hy)), lz = bft(z - bff(hz));
      int tile = i >> 5, c = i & 31;
      uint4* base = srcfrag + (size_t)tile * 64;
      base[c]      = make_uint4(pk(hx, hy), pk(hz, lx), pk(ly, lz), pk(hx, hy));
      base[32 + c] = make_uint4(pk(hz, n2h), pk(n2l, ONE_BF), pk(ONE_BF, 0u), 0u);
    } else {
      unsigned mx = bft(-2.f * bff(hx)), my = bft(-2.f * bff(hy)), mz = bft(-2.f * bff(hz));
      unsigned nx = bft(-2.f * (x - bff(hx)));
      unsigned ny = bft(-2.f * (y - bff(hy)));
      unsigned nz = bft(-2.f * (z - bff(hz)));
      dstfrag[(size_t)i * 2]     = make_uint4(pk(mx, my), pk(mz, mx), pk(my, mz), pk(nx, ny));
      dstfrag[(size_t)i * 2 + 1] = make_uint4(pk(nz, ONE_BF), pk(ONE_BF, n2h), pk(n2l, 0u), 0u);
    }
  }
}

// ---------------------------------------------------------------------------
// Fused kernel. R17: TWO src tiles per superiter (4 MFMAs) so the
// dst-direction fold is min3-batched: mn[r] = min3(mn[r], dA[r], dB[r])
// — 32 min3 per 2 tiles replaces 64 fminf (−28% inner-loop VALU).
// Trees stay per-tile (separate smin addresses).
// ---------------------------------------------------------------------------
__global__ __launch_bounds__(NT, 2) void chamfer_mfma_kernel(
    const uint4* __restrict__ srcfrag, const uint4* __restrict__ dstfrag,
    float* __restrict__ part_src, float* __restrict__ part_dst) {
  __shared__ struct {
    uint4 sfrag[2048];   // 32 KB
    unsigned smin[1024]; // 4 KB
  } sh;
  float* red = (float*)sh.sfrag;  // epilogue overlay

  int bid = blockIdx.x;
  int b = bid >> 6;
  int jp = (bid >> 2) & 15;
  int iq = bid & 3;
  int tid = threadIdx.x;

  // ---- stage: coalesced 32 KB copy
  const uint4* chunk = srcfrag + (size_t)(b * 128 + iq * 32) * 64;
  #pragma unroll
  for (int k = 0; k < 8; ++k) {
    sh.sfrag[tid + k * NT] = chunk[tid + k * NT];
  }
  #pragma unroll
  for (int k = 0; k < 4; ++k) sh.smin[tid + k * NT] = 0x7F800000u;  // +INF

  // ---- A-fragments: two dst tiles per wave, fixed all loop
  int w = tid >> 6;
  int lane = tid & 63;
  int c = lane & 31, h = lane >> 5;
  int gj = b * S + jp * 256 + w * 64 + c;
  bf16x8 A0 = __builtin_bit_cast(bf16x8, dstfrag[(size_t)gj * 2 + h]);
  bf16x8 A1 = __builtin_bit_cast(bf16x8, dstfrag[(size_t)(gj + 32) * 2 + h]);

  __syncthreads();

  f32x16 zero = {};
  f32x16 mn0, mn1;
  #pragma unroll
  for (int r = 0; r < 16; ++r) { mn0[r] = INFINITY; mn1[r] = INFINITY; }

  int t0r = 8 * w;  // per-wave rotation offset (even)
  #pragma unroll 2
  for (int it2 = 0; it2 < 16; ++it2) {
    int tA = (2 * it2 + t0r) & 31;
    int tB = tA + 1;  // t0r even -> tA even -> tB in range
    bf16x8 BfA = __builtin_bit_cast(bf16x8, sh.sfrag[tA * 64 + lane]);
    bf16x8 BfB = __builtin_bit_cast(bf16x8, sh.sfrag[tB * 64 + lane]);
    f32x16 d0A = __builtin_amdgcn_mfma_f32_32x32x16_bf16(A0, BfA, zero, 0, 0, 0);
    f32x16 d1A = __builtin_amdgcn_mfma_f32_32x32x16_bf16(A1, BfA, zero, 0, 0, 0);
    f32x16 d0B = __builtin_amdgcn_mfma_f32_32x32x16_bf16(A0, BfB, zero, 0, 0, 0);
    f32x16 d1B = __builtin_amdgcn_mfma_f32_32x32x16_bf16(A1, BfB, zero, 0, 0, 0);

    // dst-direction: min3-batched fold over both src tiles
    #pragma unroll
    for (int r = 0; r < 16; ++r) mn0[r] = min3(mn0[r], d0A[r], d0B[r]);
    #pragma unroll
    for (int r = 0; r < 16; ++r) mn1[r] = min3(mn1[r], d1A[r], d1B[r]);

    // src-direction: per-tile column trees (separate smin addresses)
    {
      float t0 = min3(d0A[0], d0A[1], d0A[2]);
      float t1 = min3(d0A[3], d0A[4], d0A[5]);
      float t2 = min3(d0A[6], d0A[7], d0A[8]);
      float t3 = min3(d0A[9], d0A[10], d0A[11]);
      float t4 = min3(d0A[12], d0A[13], d0A[14]);
      float u0 = min3(t0, t1, t2);
      float u1 = min3(t3, t4, d0A[15]);
      float s0 = min3(d1A[0], d1A[1], d1A[2]);
      float s1 = min3(d1A[3], d1A[4], d1A[5]);
      float s2 = min3(d1A[6], d1A[7], d1A[8]);
      float s3 = min3(d1A[9], d1A[10], d1A[11]);
      float s4 = min3(d1A[12], d1A[13], d1A[14]);
      float v0 = min3(s0, s1, s2);
      float v1 = min3(s3, s4, d1A[15]);
      float m = fminf(min3(u0, u1, v0), v1);
      atomicMin(&sh.smin[tA * 32 + c], __float_as_uint(fmaxf(m, 0.f)));
    }
    {
      float t0 = min3(d0B[0], d0B[1], d0B[2]);
      float t1 = min3(d0B[3], d0B[4], d0B[5]);
      float t2 = min3(d0B[6], d0B[7], d0B[8]);
      float t3 = min3(d0B[9], d0B[10], d0B[11]);
      float t4 = min3(d0B[12], d0B[13], d0B[14]);
      float u0 = min3(t0, t1, t2);
      float u1 = min3(t3, t4, d0B[15]);
      float s0 = min3(d1B[0], d1B[1], d1B[2]);
      float s1 = min3(d1B[3], d1B[4], d1B[5]);
      float s2 = min3(d1B[6], d1B[7], d1B[8]);
      float s3 = min3(d1B[9], d1B[10], d1B[11]);
      float s4 = min3(d1B[12], d1B[13], d1B[14]);
      float v0 = min3(s0, s1, s2);
      float v1 = min3(s3, s4, d1B[15]);
      float m = fminf(min3(u0, u1, v0), v1);
      atomicMin(&sh.smin[tB * 32 + c], __float_as_uint(fmaxf(m, 0.f)));
    }
  }

  // ---- src-direction flush
  __syncthreads();
  #pragma unroll
  for (int k = 0; k < 4; ++k) {
    int p = tid + k * NT;
    part_src[jp * BS + b * S + iq * 1024 + p] = __uint_as_float(sh.smin[p]);
  }
  __syncthreads();

  // ---- dst-direction: LDS transpose (stride 33) + fold + store
  #pragma unroll
  for (int r = 0; r < 16; ++r) {
    int row = w * 64 + (r & 3) + 8 * (r >> 2) + 4 * h;  // 32x32 C/D layout
    red[row * 33 + c] = mn0[r];
    red[(row + 32) * 33 + c] = mn1[r];
  }
  __syncthreads();
  {
    int row = tid;
    const float* rp = red + row * 33;
    float a0 = min3(rp[0], rp[1], rp[2]);
    float a1 = min3(rp[3], rp[4], rp[5]);
    float a2 = min3(rp[6], rp[7], rp[8]);
    float a3 = min3(rp[9], rp[10], rp[11]);
    float a4 = min3(rp[12], rp[13], rp[14]);
    float a5 = min3(rp[15], rp[16], rp[17]);
    float a6 = min3(rp[18], rp[19], rp[20]);
    float a7 = min3(rp[21], rp[22], rp[23]);
    float a8 = min3(rp[24], rp[25], rp[26]);
    float a9 = min3(rp[27], rp[28], rp[29]);
    float aa = fminf(rp[30], rp[31]);
    float b0 = min3(a0, a1, a2);
    float b1 = min3(a3, a4, a5);
    float b2 = min3(a6, a7, a8);
    float b3 = min3(a9, aa, b0);
    float m = min3(b1, b2, b3);
    part_dst[iq * BS + b * S + jp * 256 + row] = fmaxf(m, 0.f);
  }
}

// ---------------------------------------------------------------------------
// Reduce: 128 blocks x 128 thr, fold 16 src + 4 dst planes, one atomicAdd
// per block (128 total — cheap per R7).
// ---------------------------------------------------------------------------
__global__ __launch_bounds__(128) void chamfer_reduce_kernel(
    const float* __restrict__ parts, float* __restrict__ out) {
  __shared__ float red[2];
  int tid = threadIdx.x;
  int i4 = blockIdx.x * 128 + tid;  // 16384 float4 slots = BS floats

  const float4* ps = (const float4*)parts;             // 16 src planes
  const float4* pd = (const float4*)(parts + 16 * BS); // 4 dst planes

  float4 ms = ps[i4];
  #pragma unroll
  for (int j = 1; j < 16; ++j) {
    float4 t = ps[j * (BS / 4) + i4];
    ms.x = fminf(ms.x, t.x); ms.y = fminf(ms.y, t.y);
    ms.z = fminf(ms.z, t.z); ms.w = fminf(ms.w, t.w);
  }
  float4 md = pd[i4];
  #pragma unroll
  for (int j = 1; j < 4; ++j) {
    float4 t = pd[j * (BS / 4) + i4];
    md.x = fminf(md.x, t.x); md.y = fminf(md.y, t.y);
    md.z = fminf(md.z, t.z); md.w = fminf(md.w, t.w);
  }
  float v = (ms.x + ms.y + ms.z + ms.w) + (md.x + md.y + md.z + md.w);
  v *= (1.0f / (float)BS);

  #pragma unroll
  for (int off = 32; off > 0; off >>= 1) v += __shfl_down(v, off, 64);
  if ((tid & 63) == 0) red[tid >> 6] = v;
  __syncthreads();
  if (tid == 0) atomicAdd(out, red[0] + red[1]);
}

extern "C" void kernel_launch(void* const* d_in, const int* in_sizes, int n_in,
                              void* d_out, int out_size, void* d_ws, size_t ws_size,
                              hipStream_t stream) {
  const float* src_verts = (const float*)d_in[0];
  const float* dst_verts = (const float*)d_in[1];
  const int* src_idx = (const int*)d_in[2];
  const int* dst_idx = (const int*)d_in[3];
  float* out = (float*)d_out;

  float* parts = (float*)d_ws;
  float* part_src = parts;                        // [16][BS]
  float* part_dst = parts + 16 * BS;              // [4][BS]
  uint4* srcfrag = (uint4*)(parts + 21 * BS);     // 2 MB
  uint4* dstfrag = (uint4*)(parts + 29 * BS);     // 2 MB

  chamfer_prep_kernel<<<256, 256, 0, stream>>>(
      src_verts, dst_verts, src_idx, dst_idx, srcfrag, dstfrag, out);

  chamfer_mfma_kernel<<<B * 16 * 4, NT, 0, stream>>>(
      srcfrag, dstfrag, part_src, part_dst);

  chamfer_reduce_kernel<<<128, 128, 0, stream>>>(parts, out);
}